// Round 5
// baseline (9340.891 us; speedup 1.0000x reference)
//
#include <hip/hip_runtime.h>
#include <math.h>

#define NN 1000
#define INF_ 32
#define H 128
#define M 128
#define DEG 16
#define PP 2
#define OUTF 10
#define MAXM (10 * NN)        // scan length; head <= MAXM
#define QCAP (MAXM + DEG)     // only entries < MAXM are ever read
#define NT 512
#define BMAX 32               // max procs per parallel batch

// ws layout (floats): feats[NN*H] | final[NN*H] | qm[QCAP*M] | wnsT4 | wnmT4

__device__ __forceinline__ float dot4(const float4 a, const float4 b) {
    return a.x * b.x + a.y * b.y + a.z * b.z + a.w * b.w;
}

__global__ __launch_bounds__(128)
void init_kernel(const float* __restrict__ xa, const float* __restrict__ fm,
                 const float* __restrict__ enc_w, const float* __restrict__ enc_b,
                 const int* __restrict__ nstart_p,
                 float* __restrict__ feats, float* __restrict__ finalv,
                 float* __restrict__ qm) {
    int b = blockIdx.x, t = threadIdx.x;
    float acc = enc_b[t];
    const float* xr = xa + b * INF_;
#pragma unroll
    for (int k = 0; k < INF_; ++k) acc += xr[k] * enc_w[k * H + t];
    feats[b * H + t] = acc;
    finalv[b * H + t] = 0.0f;           // ws is poisoned 0xAA each launch
    if (b < nstart_p[0]) qm[(size_t)b * M + t] = fm[b * M + t];
}

// wT4[j4*128 + col] = {w[4j4+0][col], w[4j4+1][col], w[4j4+2][col], w[4j4+3][col]}
// -> per-thread K-contiguous float4 weight loads, coalesced across cols.
__global__ __launch_bounds__(256)
void transpose_kernel(const float* __restrict__ ns_w, const float* __restrict__ nm_w,
                      float4* __restrict__ wnsT4, float4* __restrict__ wnmT4) {
    const int idx = blockIdx.x * 256 + threadIdx.x;   // j4*128 + col, 8192 total
    if (idx >= 64 * 128) return;
    const int j4 = idx >> 7, col = idx & 127;
    wnsT4[idx] = make_float4(ns_w[(4 * j4 + 0) * H + col], ns_w[(4 * j4 + 1) * H + col],
                             ns_w[(4 * j4 + 2) * H + col], ns_w[(4 * j4 + 3) * H + col]);
    wnmT4[idx] = make_float4(nm_w[(4 * j4 + 0) * M + col], nm_w[(4 * j4 + 1) * M + col],
                             nm_w[(4 * j4 + 2) * M + col], nm_w[(4 * j4 + 3) * M + col]);
}

// Batched sequential ACT loop. Window-scan finds a prefix of pops whose
// parallel execution against batch-start state equals reference-sequential
// execution: cut before the first proc-candidate whose node was already
// proc'd earlier in the window (tact monotone => halted entries never flip).
__global__ __launch_bounds__(NT, 2)
void seq_kernel(const int* __restrict__ neighbors,
                const float* __restrict__ ns_b, const float* __restrict__ nm_b,
                const float* __restrict__ act_w, const float* __restrict__ act_b,
                const float* __restrict__ dec_w, const float* __restrict__ dec_b,
                const int* __restrict__ nstart_p,
                const float4* __restrict__ WN, const float4* __restrict__ WM,
                float* __restrict__ feats, float* __restrict__ finalv,
                float* __restrict__ qm, float* __restrict__ out) {
    __shared__ unsigned short s_qn[QCAP];            // 20032 B (ids < 1000)
    __shared__ float s_tact[NN];                     // 4000 B
    __shared__ int   s_mark[NN];                     // 4000 B
    __shared__ __align__(16) float s_X[BMAX][H + M]; // 32 KB batch inputs
    __shared__ __align__(16) float s_NS[BMAX][H];    // 16 KB
    __shared__ __align__(16) float s_NM[BMAX][M];    // 16 KB
    __shared__ __align__(16) float s_AMp[BMAX][M];   // 16 KB nm partials
    __shared__ float s_actw[H + M];
    __shared__ float s_nsb[H];
    __shared__ float s_nmb[M];
    __shared__ float s_z[BMAX];
    __shared__ float s_newact[BMAX];
    __shared__ int   s_pidx[BMAX];
    __shared__ int   s_pnode[BMAX];
    __shared__ int   s_wcnt[8];
    __shared__ int   s_wconf[8];
    __shared__ int   s_wcnt2[8];
    __shared__ int   s_cut2;
    __shared__ float s_g[H];
    __shared__ float s_lg[PP * OUTF];

    const int t = threadIdx.x;
    const int lane = t & 63, wid = t >> 6;
    const int col = t & 127, g = t >> 7;             // matvec mapping
    const int nstart = nstart_p[0];

    for (int i = t; i < NN; i += NT) { s_tact[i] = 0.0f; s_mark[i] = 0x7fffffff; }
    for (int i = t; i < nstart; i += NT) s_qn[i] = (unsigned short)i;
    if (t < H + M) s_actw[t] = act_w[t];
    if (t < H) { s_nsb[t] = ns_b[t]; s_nmb[t] = nm_b[t]; }
    const float actb = act_b[0];
    __syncthreads();
    const float nsb_c = s_nsb[col];
    const float nmb_c = s_nmb[col];

    int head = 0, tail = nstart;
    while (head < tail && head < MAXM) {
        // ---------------- window scan ----------------
        const int lim = min(tail, MAXM);
        const int W = min(NT, lim - head);
        int node = 0; bool proc0 = false;
        if (t < W) {
            node = (int)s_qn[head + t];
            proc0 = (s_tact[node] <= 1.0f - 1e-7f);
        }
        if (proc0) atomicMin(&s_mark[node], t);
        __syncthreads();                             // S1: marks visible
        const bool conf = proc0 && (s_mark[node] < t);
        const unsigned long long mproc = __ballot(proc0);
        const unsigned long long mconf = __ballot(conf);
        if (lane == 0) {
            s_wcnt[wid]  = __popcll(mproc);
            s_wconf[wid] = mconf ? (wid * 64 + __ffsll(mconf) - 1) : 0x7fffffff;
        }
        if (t == 0) s_cut2 = 0x7fffffff;
        __syncthreads();                             // S2
        int cut1 = s_wconf[0];
#pragma unroll
        for (int w = 1; w < 8; ++w) cut1 = min(cut1, s_wconf[w]);
        int pre = 0;
#pragma unroll
        for (int w = 0; w < 8; ++w) pre += (w < wid) ? s_wcnt[w] : 0;
        const int rank = pre + __popcll(mproc & ((1ull << lane) - 1ull));
        if (proc0 && rank == BMAX) s_cut2 = t;       // unique writer
        __syncthreads();                             // S3
        const int cutN = min(min(cut1, s_cut2), W);  // >= 1 always
        const bool proc = proc0 && (t < cutN);
        const unsigned long long mfin = __ballot(proc);
        if (lane == 0) s_wcnt2[wid] = __popcll(mfin);
        if (proc) { s_pidx[rank] = t; s_pnode[rank] = node; }
        if (proc0) s_mark[node] = 0x7fffffff;        // reset (benign same-value race)
        __syncthreads();                             // S4
        int P = 0;
#pragma unroll
        for (int w = 0; w < 8; ++w) P += s_wcnt2[w];

        if (P > 0) {
            // ---- load batch inputs X[r] = concat(feats[node_r], qm[head_r]) ----
            for (int idx = t; idx < P * 64; idx += NT) {
                const int r = idx >> 6, c4 = idx & 63;
                const int nr = s_pnode[r];
                const int hp = head + s_pidx[r];
                float4 v;
                if (c4 < 32) v = ((const float4*)(feats + (size_t)nr * H))[c4];
                else         v = ((const float4*)(qm + (size_t)hp * M))[c4 - 32];
                ((float4*)&s_X[r][0])[c4] = v;
            }
            __syncthreads();                         // S5: X ready

            // ---- gate partials: 32 lanes per row, 8 elems each (2 passes) ----
            {
                const int r0 = t >> 5, sg = t & 31;
                for (int r = r0; r < P; r += 16) {
                    const float* xr = &s_X[r][0];
                    float p = 0.0f;
#pragma unroll
                    for (int j = 0; j < 8; ++j)
                        p += xr[sg * 8 + j] * s_actw[sg * 8 + j];
#pragma unroll
                    for (int off = 16; off > 0; off >>= 1) p += __shfl_down(p, off, 32);
                    if (sg == 0) s_z[r] = p;
                }
            }

            // ---- phase 1: ns full-K + nm msg-half, adaptive rows ----
            for (int u = 0; u < BMAX / 4; ++u) {
                const int r = g + 4 * u;
                if (r >= P) break;
                const float4* Xr = (const float4*)&s_X[r][0];
                float an = 0.0f, am = 0.0f;
#pragma unroll 8
                for (int j4 = 0; j4 < 32; ++j4)
                    an += dot4(Xr[j4], WN[j4 * 128 + col]);
#pragma unroll 8
                for (int j4 = 32; j4 < 64; ++j4) {
                    an += dot4(Xr[j4], WN[j4 * 128 + col]);
                    am += dot4(Xr[j4], WM[j4 * 128 + col]);
                }
                s_NS[r][col] = fmaxf(an + nsb_c, 0.0f);
                s_AMp[r][col] = am;
            }
            __syncthreads();                         // S6: NS, AMp, z ready

            // ---- gate finalize + tact update (distinct nodes => safe) ----
            if (t < P) {
                const float z = s_z[t] + actb;
                const float cand = 1.0f / (1.0f + expf(-z));
                const int nr = s_pnode[t];
                const float ta = s_tact[nr];
                const float na = (ta + cand > 1.0f) ? (1.0f - ta) : cand;
                s_newact[t] = na;
                s_tact[nr] = ta + na;
            }
            // ---- qn enqueue ----
            if (t < P * DEG) {
                const int q = tail + t;              // q = tail + 16r + d
                if (q < QCAP)
                    s_qn[q] = (unsigned short)neighbors[s_pnode[t >> 4] * DEG + (t & 15)];
            }
            // ---- phase 2: nm ns-half, adaptive rows ----
            for (int u = 0; u < BMAX / 4; ++u) {
                const int r = g + 4 * u;
                if (r >= P) break;
                const float4* Nr = (const float4*)&s_NS[r][0];
                float am = s_AMp[r][col];
#pragma unroll 8
                for (int k4 = 0; k4 < 32; ++k4)
                    am += dot4(Nr[k4], WM[k4 * 128 + col]);
                s_NM[r][col] = am + nmb_c;
            }
            __syncthreads();                         // S7: NM, newact ready

            // ---- feats / finalv updates (distinct rows) ----
            for (int u = 0; u < BMAX / 4; ++u) {
                const int r = g + 4 * u;
                if (r >= P) break;
                const int nr = s_pnode[r];
                const float nsv = s_NS[r][col];
                feats[(size_t)nr * H + col] = nsv;
                finalv[(size_t)nr * H + col] += nsv * s_newact[r];
            }
            // ---- qm enqueue: P*16 rows, float4 coalesced ----
            {
                float4* qm4 = (float4*)qm;
                const int total = P * DEG * 32;
                for (int idx = t; idx < total; idx += NT) {
                    const int c4 = idx & 31;
                    const int row = idx >> 5;        // 0 .. P*16-1
                    const int r = row >> 4;
                    const int q = tail + row;
                    if (q < QCAP)
                        qm4[(size_t)q * 32 + c4] = ((const float4*)&s_NM[r][0])[c4];
                }
            }
            tail += DEG * P;
        }
        head += cutN;
        __syncthreads();                             // S8: state ready for next window
    }

    // ---- readout: g = colsum(final); logits = g@dec_w+dec_b; log_softmax ----
    if (t < H) {
        float g0 = 0, g1 = 0, g2 = 0, g3 = 0;
        for (int n = 0; n < NN; n += 4) {
            g0 += finalv[(n + 0) * H + t];
            g1 += finalv[(n + 1) * H + t];
            g2 += finalv[(n + 2) * H + t];
            g3 += finalv[(n + 3) * H + t];
        }
        s_g[t] = (g0 + g1) + (g2 + g3);
    }
    __syncthreads();
    if (t < PP * OUTF) {
        const int pp = t / OUTF, o = t % OUTF;
        float acc = dec_b[pp * OUTF + o];
        for (int h = 0; h < H; ++h) acc += s_g[h] * dec_w[(pp * H + h) * OUTF + o];
        s_lg[t] = acc;
    }
    __syncthreads();
    if (t < PP * OUTF) {
        const int pp = t / OUTF;
        float mx = -INFINITY;
        for (int o = 0; o < OUTF; ++o) mx = fmaxf(mx, s_lg[pp * OUTF + o]);
        float s = 0.0f;
        for (int o = 0; o < OUTF; ++o) s += expf(s_lg[pp * OUTF + o] - mx);
        out[t] = s_lg[t] - (mx + logf(s));
    }
}

extern "C" void kernel_launch(void* const* d_in, const int* in_sizes, int n_in,
                              void* d_out, int out_size, void* d_ws, size_t ws_size,
                              hipStream_t stream) {
    const float* xa        = (const float*)d_in[0];
    const float* fm        = (const float*)d_in[1];
    const int*   neighbors = (const int*)  d_in[2];
    const int*   nstart_p  = (const int*)  d_in[3];
    const float* enc_w     = (const float*)d_in[4];
    const float* enc_b     = (const float*)d_in[5];
    const float* ns_w      = (const float*)d_in[6];
    const float* ns_b      = (const float*)d_in[7];
    const float* nm_w      = (const float*)d_in[8];
    const float* nm_b      = (const float*)d_in[9];
    const float* act_w     = (const float*)d_in[10];
    const float* act_b     = (const float*)d_in[11];
    const float* dec_w     = (const float*)d_in[12];
    const float* dec_b     = (const float*)d_in[13];
    float* out = (float*)d_out;

    float*  feats  = (float*)d_ws;
    float*  finalv = feats + NN * H;
    float*  qm     = finalv + NN * H;                 // QCAP*M floats ≈ 5.1 MB
    float4* wnsT4  = (float4*)(qm + (size_t)QCAP * M);
    float4* wnmT4  = wnsT4 + 64 * 128;                // 128 KB each

    init_kernel<<<NN, 128, 0, stream>>>(xa, fm, enc_w, enc_b, nstart_p,
                                        feats, finalv, qm);
    transpose_kernel<<<32, 256, 0, stream>>>(ns_w, nm_w, wnsT4, wnmT4);
    seq_kernel<<<1, NT, 0, stream>>>(neighbors, ns_b, nm_b,
                                     act_w, act_b, dec_w, dec_b, nstart_p,
                                     wnsT4, wnmT4,
                                     feats, finalv, qm, out);
}

// Round 6
// 5771.090 us; speedup vs baseline: 1.6186x; 1.6186x over previous
//
#include <hip/hip_runtime.h>
#include <math.h>

#define NN 1000
#define INF_ 32
#define H 128
#define M 128
#define DEG 16
#define PP 2
#define OUTF 10
#define MAXM (10 * NN)        // scan length; head <= MAXM
#define QCAP (MAXM + DEG)     // only entries < MAXM are ever read
#define NT 512
#define PB 32                 // candidate cap per window == NM slot count

// ws layout (floats): feats[NN*H] | final[NN*H] | qm[QCAP*M] | wnsT4 | wnmT4

__device__ __forceinline__ float dot4(const float4 a, const float4 b) {
    return a.x * b.x + a.y * b.y + a.z * b.z + a.w * b.w;
}

__global__ __launch_bounds__(128)
void init_kernel(const float* __restrict__ xa, const float* __restrict__ fm,
                 const float* __restrict__ enc_w, const float* __restrict__ enc_b,
                 const int* __restrict__ nstart_p,
                 float* __restrict__ feats, float* __restrict__ finalv,
                 float* __restrict__ qm) {
    int b = blockIdx.x, t = threadIdx.x;
    float acc = enc_b[t];
    const float* xr = xa + b * INF_;
#pragma unroll
    for (int k = 0; k < INF_; ++k) acc += xr[k] * enc_w[k * H + t];
    feats[b * H + t] = acc;
    finalv[b * H + t] = 0.0f;           // ws is poisoned 0xAA each launch
    if (b < nstart_p[0]) qm[(size_t)b * M + t] = fm[b * M + t];
}

// wT4[j4*128 + col] = {w[4j4+0][col], .., w[4j4+3][col]} — K-contiguous float4.
__global__ __launch_bounds__(256)
void transpose_kernel(const float* __restrict__ ns_w, const float* __restrict__ nm_w,
                      float4* __restrict__ wnsT4, float4* __restrict__ wnmT4) {
    const int idx = blockIdx.x * 256 + threadIdx.x;   // j4*128 + col, 8192 total
    if (idx >= 64 * 128) return;
    const int j4 = idx >> 7, col = idx & 127;
    wnsT4[idx] = make_float4(ns_w[(4 * j4 + 0) * H + col], ns_w[(4 * j4 + 1) * H + col],
                             ns_w[(4 * j4 + 2) * H + col], ns_w[(4 * j4 + 3) * H + col]);
    wnmT4[idx] = make_float4(nm_w[(4 * j4 + 0) * M + col], nm_w[(4 * j4 + 1) * M + col],
                             nm_w[(4 * j4 + 2) * M + col], nm_w[(4 * j4 + 3) * M + col]);
}

// phase1: an = X[0:256) @ ns_w col; am = X[128:256) @ nm_w[128:256) col.
// U rows per thread (r = g + 4u), weights loaded ONCE per j4 and shared.
template<int U>
__device__ __forceinline__ void mv_phase1(const float4* __restrict__ WN,
                                          const float4* __restrict__ WM,
                                          const float* sX, float* sNS, float* sNM,
                                          int col, int g, int Pr, int base,
                                          float nsb_c) {
    float an[U], am[U];
#pragma unroll
    for (int u = 0; u < U; ++u) { an[u] = 0.0f; am[u] = 0.0f; }
    const float4* Xp[U];
#pragma unroll
    for (int u = 0; u < U; ++u) Xp[u] = (const float4*)(sX + (g + 4 * u) * (H + M));
#pragma unroll 4
    for (int j4 = 0; j4 < 32; ++j4) {
        const float4 w = WN[j4 * 128 + col];
#pragma unroll
        for (int u = 0; u < U; ++u) an[u] += dot4(Xp[u][j4], w);
    }
#pragma unroll 4
    for (int j4 = 32; j4 < 64; ++j4) {
        const float4 w = WN[j4 * 128 + col];
        const float4 m = WM[j4 * 128 + col];
#pragma unroll
        for (int u = 0; u < U; ++u) {
            const float4 x = Xp[u][j4];
            an[u] += dot4(x, w);
            am[u] += dot4(x, m);
        }
    }
#pragma unroll
    for (int u = 0; u < U; ++u) {
        const int r = g + 4 * u;
        if (r < Pr) {
            sNS[r * H + col] = fmaxf(an[u] + nsb_c, 0.0f);
            sNM[(base + r) * M + col] = am[u];
        }
    }
}

// phase2: am += NS[0:128) @ nm_w[0:128) col; finalize NM.
template<int U>
__device__ __forceinline__ void mv_phase2(const float4* __restrict__ WM,
                                          const float* sNS, float* sNM,
                                          int col, int g, int Pr, int base,
                                          float nmb_c) {
    float am[U];
#pragma unroll
    for (int u = 0; u < U; ++u) am[u] = 0.0f;
    const float4* Np[U];
#pragma unroll
    for (int u = 0; u < U; ++u) Np[u] = (const float4*)(sNS + (g + 4 * u) * H);
#pragma unroll 4
    for (int k4 = 0; k4 < 32; ++k4) {
        const float4 m = WM[k4 * 128 + col];
#pragma unroll
        for (int u = 0; u < U; ++u) am[u] += dot4(Np[u][k4], m);
    }
#pragma unroll
    for (int u = 0; u < U; ++u) {
        const int r = g + 4 * u;
        if (r < Pr) {
            float* p = sNM + (base + r) * M + col;
            *p = *p + am[u] + nmb_c;
        }
    }
}

// Full-window rank decomposition: pop a 512-entry window (cut only at the
// (PB+1)-th candidate). Per rank round, atomicMin picks each node's earliest
// unprocessed candidate; those distinct-node rows run as one batched matvec;
// tact/feats update sequentially-equivalently. Enqueue order via prefix sum
// of final proc flags (queue order preserved).
__global__ __launch_bounds__(NT, 1)
void seq_kernel(const int* __restrict__ neighbors,
                const float* __restrict__ ns_b, const float* __restrict__ nm_b,
                const float* __restrict__ act_w, const float* __restrict__ act_b,
                const float* __restrict__ dec_w, const float* __restrict__ dec_b,
                const int* __restrict__ nstart_p,
                const float4* __restrict__ WN, const float4* __restrict__ WM,
                float* __restrict__ feats, float* __restrict__ finalv,
                float* __restrict__ qm, float* __restrict__ out) {
    __shared__ unsigned short s_qn[QCAP];                 // 20032 B
    __shared__ float s_tact[NN];                          // 4000 B
    __shared__ int   s_mark[NN];                          // 4000 B
    __shared__ __align__(16) float s_X[PB * (H + M)];     // 32 KB (round rows)
    __shared__ __align__(16) float s_NS[PB * H];          // 16 KB (round rows)
    __shared__ __align__(16) float s_NM[PB * M];          // 16 KB (by slot)
    __shared__ float s_actw[H + M];
    __shared__ float s_nsb[H];
    __shared__ float s_nmb[M];
    __shared__ float s_rz[PB];
    __shared__ float s_rna[PB];
    __shared__ int   s_rnode[PB];
    __shared__ int   s_rentry[PB];
    __shared__ short s_eslot[NT];
    __shared__ unsigned char s_flag[NT];
    __shared__ short s_order[PB];
    __shared__ int   s_wa[8], s_wb[8], s_wc[8];
    __shared__ int   s_cut;
    __shared__ float s_g[H];
    __shared__ float s_lg[PP * OUTF];

    const int t = threadIdx.x;
    const int lane = t & 63, wid = t >> 6;
    const int col = t & 127, g = t >> 7;
    const int nstart = nstart_p[0];

    for (int i = t; i < NN; i += NT) { s_tact[i] = 0.0f; s_mark[i] = 0x7fffffff; }
    for (int i = t; i < nstart; i += NT) s_qn[i] = (unsigned short)i;
    if (t < H + M) s_actw[t] = act_w[t];
    if (t < H) { s_nsb[t] = ns_b[t]; s_nmb[t] = nm_b[t]; }
    const float actb = act_b[0];
    __syncthreads();
    const float nsb_c = s_nsb[col];
    const float nmb_c = s_nmb[col];

    int head = 0, tail = nstart;
    for (;;) {
        const int lim = min(tail, MAXM);
        if (head >= lim) break;
        const int W = min(NT, lim - head);

        // ---- classify candidates & cut window at (PB+1)-th candidate ----
        int node = 0; bool cand0 = false;
        if (t < W) {
            node = (int)s_qn[head + t];
            cand0 = (s_tact[node] <= 1.0f - 1e-7f);
        }
        const unsigned long long mc = __ballot(cand0);
        if (lane == 0) s_wa[wid] = __popcll(mc);
        if (t == 0) s_cut = 0x7fffffff;
        s_flag[t] = 0;
        __syncthreads();                                  // B1
        int pre = 0;
#pragma unroll
        for (int w = 0; w < 8; ++w) pre += (w < wid) ? s_wa[w] : 0;
        const int crank = pre + __popcll(mc & ((1ull << lane) - 1ull));
        if (cand0 && crank == PB) s_cut = t;              // unique writer
        __syncthreads();                                  // B2
        const int Wp = min(W, s_cut);
        bool remaining = cand0 && (t < Wp);

        // ---------------- rank rounds ----------------
        int base = 0;
        for (;;) {
            const bool rem2 = remaining && (s_tact[node] <= 1.0f - 1e-7f);
            if (rem2) atomicMin(&s_mark[node], t);
            __syncthreads();                              // R1
            const bool win = rem2 && (s_mark[node] == t);
            const unsigned long long mw = __ballot(win);
            if (lane == 0) s_wb[wid] = __popcll(mw);
            __syncthreads();                              // R2
            int Pr = 0, preb = 0;
#pragma unroll
            for (int w = 0; w < 8; ++w) { Pr += s_wb[w]; preb += (w < wid) ? s_wb[w] : 0; }
            if (Pr == 0) break;
            const int wrank = preb + __popcll(mw & ((1ull << lane) - 1ull));
            if (win) {
                s_rnode[wrank] = node;
                s_rentry[wrank] = t;
                s_eslot[t] = (short)(base + wrank);
                s_flag[t] = 1;
            }
            if (rem2) s_mark[node] = 0x7fffffff;          // reset (same-value ok)
            remaining = rem2 && !win;
            __syncthreads();                              // R3

            // ---- stage X[j] = concat(feats[node_j], qm[head+entry_j]) ----
            for (int idx = t; idx < Pr * 64; idx += NT) {
                const int j = idx >> 6, c4 = idx & 63;
                const int nr = s_rnode[j];
                const int hp = head + s_rentry[j];
                float4 v;
                if (c4 < 32) v = ((const float4*)(feats + (size_t)nr * H))[c4];
                else         v = ((const float4*)(qm + (size_t)hp * M))[c4 - 32];
                ((float4*)(s_X + j * (H + M)))[c4] = v;
            }
            __syncthreads();                              // R4

            // ---- gate partials (R4 form, bit-identical) ----
            {
                const int r0 = t >> 5, sg = t & 31;
                for (int r = r0; r < Pr; r += 16) {
                    const float* xr = s_X + r * (H + M);
                    float p = 0.0f;
#pragma unroll
                    for (int j = 0; j < 8; ++j)
                        p += xr[sg * 8 + j] * s_actw[sg * 8 + j];
#pragma unroll
                    for (int off = 16; off > 0; off >>= 1) p += __shfl_down(p, off, 32);
                    if (sg == 0) s_rz[r] = p;
                }
            }
            // ---- matvec phase 1 (one weight stream, up to 32 rows) ----
            if      (Pr <= 4)  mv_phase1<1>(WN, WM, s_X, s_NS, s_NM, col, g, Pr, base, nsb_c);
            else if (Pr <= 8)  mv_phase1<2>(WN, WM, s_X, s_NS, s_NM, col, g, Pr, base, nsb_c);
            else if (Pr <= 16) mv_phase1<4>(WN, WM, s_X, s_NS, s_NM, col, g, Pr, base, nsb_c);
            else               mv_phase1<8>(WN, WM, s_X, s_NS, s_NM, col, g, Pr, base, nsb_c);
            __syncthreads();                              // R5

            // ---- gate finalize + tact (distinct nodes per round) ----
            if (t < Pr) {
                const float z = s_rz[t] + actb;
                const float cand = 1.0f / (1.0f + expf(-z));
                const int nr = s_rnode[t];
                const float ta = s_tact[nr];
                const float na = (ta + cand > 1.0f) ? (1.0f - ta) : cand;
                s_rna[t] = na;
                s_tact[nr] = ta + na;
            }
            __syncthreads();                              // R6

            // ---- feats/finalv updates + matvec phase 2 ----
            for (int r = g; r < Pr; r += 4) {
                const int nr = s_rnode[r];
                const float nsv = s_NS[r * H + col];
                feats[(size_t)nr * H + col] = nsv;
                finalv[(size_t)nr * H + col] += nsv * s_rna[r];
            }
            if      (Pr <= 4)  mv_phase2<1>(WM, s_NS, s_NM, col, g, Pr, base, nmb_c);
            else if (Pr <= 8)  mv_phase2<2>(WM, s_NS, s_NM, col, g, Pr, base, nmb_c);
            else if (Pr <= 16) mv_phase2<4>(WM, s_NS, s_NM, col, g, Pr, base, nmb_c);
            else               mv_phase2<8>(WM, s_NS, s_NM, col, g, Pr, base, nmb_c);
            base += Pr;
            __syncthreads();                              // R7
        }

        // ---------------- enqueue (queue-order via prefix sum) ----------------
        const bool pf = (s_flag[t] != 0);
        const unsigned long long mf = __ballot(pf);
        if (lane == 0) s_wc[wid] = __popcll(mf);
        __syncthreads();                                  // B3
        int T = 0, prec = 0;
#pragma unroll
        for (int w = 0; w < 8; ++w) { T += s_wc[w]; prec += (w < wid) ? s_wc[w] : 0; }
        if (pf) s_order[prec + __popcll(mf & ((1ull << lane) - 1ull))] = (short)t;
        __syncthreads();                                  // B4
        for (int idx = t; idx < T * DEG; idx += NT) {
            const int j = idx >> 4;
            const int nd = (int)s_qn[head + (int)s_order[j]];
            const int q = tail + idx;
            if (q < QCAP)
                s_qn[q] = (unsigned short)neighbors[nd * DEG + (idx & 15)];
        }
        {
            float4* qm4 = (float4*)qm;
            const int total = T * DEG * 32;
            for (int idx = t; idx < total; idx += NT) {
                const int c4 = idx & 31;
                const int row = idx >> 5;
                const int slot = (int)s_eslot[(int)s_order[row >> 4]];
                const int q = tail + row;
                if (q < QCAP)
                    qm4[(size_t)q * 32 + c4] = ((const float4*)(s_NM + slot * M))[c4];
            }
        }
        tail += DEG * T;
        head += Wp;
        __syncthreads();                                  // B5
    }

    // ---- readout: g = colsum(final); logits = g@dec_w+dec_b; log_softmax ----
    if (t < H) {
        float g0 = 0, g1 = 0, g2 = 0, g3 = 0;
        for (int n = 0; n < NN; n += 4) {
            g0 += finalv[(n + 0) * H + t];
            g1 += finalv[(n + 1) * H + t];
            g2 += finalv[(n + 2) * H + t];
            g3 += finalv[(n + 3) * H + t];
        }
        s_g[t] = (g0 + g1) + (g2 + g3);
    }
    __syncthreads();
    if (t < PP * OUTF) {
        const int pp = t / OUTF, o = t % OUTF;
        float acc = dec_b[pp * OUTF + o];
        for (int h = 0; h < H; ++h) acc += s_g[h] * dec_w[(pp * H + h) * OUTF + o];
        s_lg[t] = acc;
    }
    __syncthreads();
    if (t < PP * OUTF) {
        const int pp = t / OUTF;
        float mx = -INFINITY;
        for (int o = 0; o < OUTF; ++o) mx = fmaxf(mx, s_lg[pp * OUTF + o]);
        float s = 0.0f;
        for (int o = 0; o < OUTF; ++o) s += expf(s_lg[pp * OUTF + o] - mx);
        out[t] = s_lg[t] - (mx + logf(s));
    }
}

extern "C" void kernel_launch(void* const* d_in, const int* in_sizes, int n_in,
                              void* d_out, int out_size, void* d_ws, size_t ws_size,
                              hipStream_t stream) {
    const float* xa        = (const float*)d_in[0];
    const float* fm        = (const float*)d_in[1];
    const int*   neighbors = (const int*)  d_in[2];
    const int*   nstart_p  = (const int*)  d_in[3];
    const float* enc_w     = (const float*)d_in[4];
    const float* enc_b     = (const float*)d_in[5];
    const float* ns_w      = (const float*)d_in[6];
    const float* ns_b      = (const float*)d_in[7];
    const float* nm_w      = (const float*)d_in[8];
    const float* nm_b      = (const float*)d_in[9];
    const float* act_w     = (const float*)d_in[10];
    const float* act_b     = (const float*)d_in[11];
    const float* dec_w     = (const float*)d_in[12];
    const float* dec_b     = (const float*)d_in[13];
    float* out = (float*)d_out;

    float*  feats  = (float*)d_ws;
    float*  finalv = feats + NN * H;
    float*  qm     = finalv + NN * H;                 // QCAP*M floats ≈ 5.1 MB
    float4* wnsT4  = (float4*)(qm + (size_t)QCAP * M);
    float4* wnmT4  = wnsT4 + 64 * 128;                // 128 KB each

    init_kernel<<<NN, 128, 0, stream>>>(xa, fm, enc_w, enc_b, nstart_p,
                                        feats, finalv, qm);
    transpose_kernel<<<32, 256, 0, stream>>>(ns_w, nm_w, wnsT4, wnmT4);
    seq_kernel<<<1, NT, 0, stream>>>(neighbors, ns_b, nm_b,
                                     act_w, act_b, dec_w, dec_b, nstart_p,
                                     wnsT4, wnmT4,
                                     feats, finalv, qm, out);
}